// Round 8
// baseline (420.464 us; speedup 1.0000x reference)
//
#include <hip/hip_runtime.h>
#include <hip/hip_bf16.h>
#include <hip/hip_fp16.h>

#define N_NODES 50000
#define N_EDGES 800000
#define IN_CH 64
#define EDGE_DIM 8
#define HIDDEN 128
#define NUM_GRAPHS 256
#define NPASS 2
#define PASS_W ((N_NODES + NPASS - 1) / NPASS)   // 25000
#define QSCALE 256.0f
#define QINV   (1.0f / 256.0f)

typedef __attribute__((ext_vector_type(8))) _Float16 half8;
typedef __attribute__((ext_vector_type(4))) float floatx4;
typedef __attribute__((ext_vector_type(2))) float floatx2;
typedef __attribute__((ext_vector_type(4))) int intx4;

static __device__ __forceinline__ __half2 u2h(int u) {
    union { int i; __half2 h; } cv; cv.i = u; return cv.h;
}
static __device__ __forceinline__ int h2u(__half2 h) {
    union { __half2 h; int i; } cv; cv.h = h; return cv.i;
}
// fp8 e4m3 helpers (gfx950 OCP)
static __device__ __forceinline__ unsigned char f32_to_fp8(float v) {
    int pk = __builtin_amdgcn_cvt_pk_fp8_f32(v, v, 0, false);
    return (unsigned char)(pk & 0xff);
}

// ===========================================================================
// CSR build: histogram (fused with fp8/Wt conversions), scan, then NPASS
// dst-range RECORD scatter passes. Edge order within a node = atomic arrival
// order (nondeterministic) -- harmless: gathers accumulate in int32 fixed
// point (order-insensitive).
// ===========================================================================
#define XH_ELEMS (N_NODES * IN_CH)

__global__ __launch_bounds__(256) void hist_cvt_kernel(
    const int* __restrict__ dst, int* __restrict__ deg,
    const float* __restrict__ x, unsigned char* __restrict__ xh8,
    const float* __restrict__ W1, const float* __restrict__ W2,
    const float* __restrict__ W3,
    _Float16* __restrict__ Wt1, _Float16* __restrict__ Wt2,
    _Float16* __restrict__ Wt3, int E)
{
    int i = blockIdx.x * blockDim.x + threadIdx.x;
    if (i < E) atomicAdd(&deg[dst[i]], 1);
    int idx = i;
    if (idx < XH_ELEMS) { xh8[idx] = f32_to_fp8(x[idx]); return; }
    idx -= XH_ELEMS;
    if (idx < 128 * IN_CH) {
        int n = idx / IN_CH, k = idx - n * IN_CH;
        Wt1[idx] = (_Float16)W1[k * 128 + n];
        return;
    }
    idx -= 128 * IN_CH;
    if (idx < 128 * HIDDEN) {
        int n = idx / HIDDEN, k = idx - n * HIDDEN;
        Wt2[idx] = (_Float16)W2[k * 128 + n];
        return;
    }
    idx -= 128 * HIDDEN;
    if (idx < 128 * HIDDEN) {
        int n = idx / HIDDEN, k = idx - n * HIDDEN;
        Wt3[idx] = (_Float16)W3[k * 128 + n];
    }
}

__global__ __launch_bounds__(256) void scan1_kernel(
    const int* __restrict__ deg, int* __restrict__ incl,
    int* __restrict__ blockSums, int N)
{
    __shared__ int s[256];
    int b = blockIdx.x, t = threadIdx.x;
    int i0 = b * 512 + 2 * t;
    int a0 = (i0 < N) ? deg[i0] : 0;
    int a1 = (i0 + 1 < N) ? deg[i0 + 1] : 0;
    int ps = a0 + a1;
    s[t] = ps;
    __syncthreads();
    for (int off = 1; off < 256; off <<= 1) {
        int v = (t >= off) ? s[t - off] : 0;
        __syncthreads();
        s[t] += v;
        __syncthreads();
    }
    int exclp = s[t] - ps;
    if (i0 < N)     incl[i0]     = exclp + a0;
    if (i0 + 1 < N) incl[i0 + 1] = exclp + a0 + a1;
    if (t == 255) blockSums[b] = s[255];
}

__global__ __launch_bounds__(128) void scan2_kernel(int* __restrict__ blockSums, int B)
{
    __shared__ int s[128];
    int t = threadIdx.x;
    int v = (t < B) ? blockSums[t] : 0;
    s[t] = v;
    __syncthreads();
    for (int off = 1; off < 128; off <<= 1) {
        int u = (t >= off) ? s[t - off] : 0;
        __syncthreads();
        s[t] += u;
        __syncthreads();
    }
    if (t < B) blockSums[t] = s[t] - v;   // exclusive
}

__global__ __launch_bounds__(256) void scan3_kernel(
    const int* __restrict__ incl, const int* __restrict__ deg,
    const int* __restrict__ blockSums, int* __restrict__ rowptr,
    int* __restrict__ pos, int N)
{
    int i = blockIdx.x * blockDim.x + threadIdx.x;
    if (i >= N) return;
    int v = incl[i] - deg[i] + blockSums[i >> 9];
    rowptr[i] = v;
    pos[i] = v;
}

// One dst-range RECORD scatter pass (writes src_s + fp16 edge record).
__global__ __launch_bounds__(256) void scatter_rec_kernel(
    const int* __restrict__ dst, const int* __restrict__ src,
    const float* __restrict__ ea, int* __restrict__ pos,
    int* __restrict__ src_s, __half* __restrict__ ea16, int lo, int E)
{
    int e = blockIdx.x * blockDim.x + threadIdx.x;
    if (e >= E) return;
    int d = dst[e];
    if ((unsigned)(d - lo) >= (unsigned)PASS_W) return;
    int p = atomicAdd(&pos[d], 1);
    __builtin_nontemporal_store(src[e], &src_s[p]);
    const float4* q = (const float4*)(ea + (size_t)e * EDGE_DIM);
    float4 a = q[0], b = q[1];
    intx4 r;
    r.x = h2u(__floats2half2_rn(a.x, a.y));
    r.y = h2u(__floats2half2_rn(a.z, a.w));
    r.z = h2u(__floats2half2_rn(b.x, b.y));
    r.w = h2u(__floats2half2_rn(b.z, b.w));
    __builtin_nontemporal_store(r, (intx4*)(ea16 + (size_t)p * EDGE_DIM));
}

// ===========================================================================
// FUSED layer: gather-aggregate (fp8 table, int32 fixed-point acc) into an
// LDS tile of 32 node-rows, then the block's 4 waves run the MFMA GEMM
// out = relu(xs @ W + b) on that tile (each wave: 2 of 8 col-tiles).
// Removes the xs HBM round-trip and one dispatch per layer.
//   xs[n][j] = h[n][j] + sum_e relu( h[src][j] + (ea@We+be)[j] )
// Numeric path identical to the R7 verified kernels.
// ===========================================================================
#define BF 8   // edges in flight per wave

template<int K, bool OUT8>
__global__ __launch_bounds__(256) void layer_fused_kernel(
    const unsigned char* __restrict__ h8,   // [N,K] fp8 gather table
    const int*    __restrict__ src_s,       // [E] CSR order
    const __half* __restrict__ ea16,        // [E,8] fp16 CSR order
    const int*    __restrict__ rowptr,      // [N]
    const int*    __restrict__ deg,         // [N]
    const float*  __restrict__ We,          // [8,K]
    const float*  __restrict__ be,          // [K]
    const _Float16* __restrict__ Wt,        // [128][K] fp16 (W transposed)
    const float*  __restrict__ bias,        // [128]
    _Float16*     __restrict__ out16,       // [N,128] fp16 (if !OUT8)
    unsigned char* __restrict__ out8,       // [N,128] fp8  (if OUT8)
    int N)
{
    __shared__ _Float16 xsl[32][K + 8];     // +8 pad: 16B-aligned rows, fewer bank hits
    int wave = threadIdx.x >> 6;
    int l    = threadIdx.x & 63;
    int m0   = blockIdx.x * 32;

    // ---------------- phase 1: gather 8 nodes per wave into LDS ----------
    if constexpr (K == 128) {
        int j0 = 2 * l;
        __half2 hw[8];
        #pragma unroll
        for (int k = 0; k < 8; ++k) {
            float2 wv = *(const float2*)&We[k * 128 + j0];
            hw[k] = __floats2half2_rn(wv.x, wv.y);
        }
        float2 bevf = *(const float2*)&be[j0];
        __half2 bev2 = __floats2half2_rn(bevf.x, bevf.y);

        for (int i = 0; i < 8; ++i) {
            int nl = wave * 8 + i;
            int n  = m0 + nl;
            if (n >= N) { *(__half2*)&xsl[nl][j0] = __floats2half2_rn(0.f, 0.f); continue; }

            int start = __builtin_amdgcn_readfirstlane(rowptr[n]);
            int dg    = __builtin_amdgcn_readfirstlane(deg[n]);

            unsigned short selfraw = *(const unsigned short*)&h8[(size_t)n * 128 + j0];
            floatx2 hf = __builtin_amdgcn_cvt_pk_f32_fp8((int)selfraw, false);
            int acci0 = 0, acci1 = 0;

            int nb = dg / BF;
            int base = start;
            for (int b = 0; b < nb; ++b, base += BF) {
                int sid[BF];
                #pragma unroll
                for (int t = 0; t < BF; ++t)
                    sid[t] = __builtin_amdgcn_readfirstlane(
                        __builtin_nontemporal_load(&src_s[base + t]));
                unsigned short hraw[BF];
                #pragma unroll
                for (int t = 0; t < BF; ++t)
                    hraw[t] = *(const unsigned short*)&h8[(size_t)sid[t] * 128 + j0];
                intx4 eav[BF];
                #pragma unroll
                for (int t = 0; t < BF; ++t)
                    eav[t] = __builtin_nontemporal_load(
                        (const intx4*)&ea16[(size_t)(base + t) * 8]);

                #pragma unroll
                for (int t = 0; t < BF; ++t) {
                    __half2 e01 = u2h(eav[t].x), e23 = u2h(eav[t].y);
                    __half2 e45 = u2h(eav[t].z), e67 = u2h(eav[t].w);
                    __half2 m = __hfma2(__low2half2(e01),  hw[0], bev2);
                    m = __hfma2(__high2half2(e01), hw[1], m);
                    m = __hfma2(__low2half2(e23),  hw[2], m);
                    m = __hfma2(__high2half2(e23), hw[3], m);
                    m = __hfma2(__low2half2(e45),  hw[4], m);
                    m = __hfma2(__high2half2(e45), hw[5], m);
                    m = __hfma2(__low2half2(e67),  hw[6], m);
                    m = __hfma2(__high2half2(e67), hw[7], m);
                    floatx2 hs = __builtin_amdgcn_cvt_pk_f32_fp8((int)hraw[t], false);
                    float m0f = __half2float(__low2half(m))  + hs.x;
                    float m1f = __half2float(__high2half(m)) + hs.y;
                    acci0 += (int)((m0f > 0.0f ? m0f : 0.0f) * QSCALE);
                    acci1 += (int)((m1f > 0.0f ? m1f : 0.0f) * QSCALE);
                }
            }
            int end = start + dg;
            for (int idx = base; idx < end; ++idx) {
                int s = __builtin_amdgcn_readfirstlane(src_s[idx]);
                unsigned short hr = *(const unsigned short*)&h8[(size_t)s * 128 + j0];
                intx4 ev = __builtin_nontemporal_load((const intx4*)&ea16[(size_t)idx * 8]);
                __half2 e01 = u2h(ev.x), e23 = u2h(ev.y), e45 = u2h(ev.z), e67 = u2h(ev.w);
                __half2 m = __hfma2(__low2half2(e01),  hw[0], bev2);
                m = __hfma2(__high2half2(e01), hw[1], m);
                m = __hfma2(__low2half2(e23),  hw[2], m);
                m = __hfma2(__high2half2(e23), hw[3], m);
                m = __hfma2(__low2half2(e45),  hw[4], m);
                m = __hfma2(__high2half2(e45), hw[5], m);
                m = __hfma2(__low2half2(e67),  hw[6], m);
                m = __hfma2(__high2half2(e67), hw[7], m);
                floatx2 hs = __builtin_amdgcn_cvt_pk_f32_fp8((int)hr, false);
                float m0f = __half2float(__low2half(m))  + hs.x;
                float m1f = __half2float(__high2half(m)) + hs.y;
                acci0 += (int)((m0f > 0.0f ? m0f : 0.0f) * QSCALE);
                acci1 += (int)((m1f > 0.0f ? m1f : 0.0f) * QSCALE);
            }
            float acc0 = hf.x + (float)acci0 * QINV;
            float acc1 = hf.y + (float)acci1 * QINV;
            *(__half2*)&xsl[nl][j0] = __floats2half2_rn(acc0, acc1);
        }
    } else {            // K == 64: one feature per lane
        int j = l;
        __half2 w2[4];
        #pragma unroll
        for (int p = 0; p < 4; ++p)
            w2[p] = __floats2half2_rn(We[(2 * p) * 64 + j], We[(2 * p + 1) * 64 + j]);
        float bej = be[j];

        for (int i = 0; i < 8; ++i) {
            int nl = wave * 8 + i;
            int n  = m0 + nl;
            if (n >= N) { xsl[nl][j] = (_Float16)0.0f; continue; }

            int start = __builtin_amdgcn_readfirstlane(rowptr[n]);
            int dg    = __builtin_amdgcn_readfirstlane(deg[n]);

            float selff = __builtin_amdgcn_cvt_f32_fp8((int)h8[(size_t)n * 64 + j], 0);
            int acci = 0;

            int nb = dg / BF;
            int base = start;
            for (int b = 0; b < nb; ++b, base += BF) {
                int sid[BF];
                #pragma unroll
                for (int t = 0; t < BF; ++t)
                    sid[t] = __builtin_amdgcn_readfirstlane(
                        __builtin_nontemporal_load(&src_s[base + t]));
                unsigned char hraw[BF];
                #pragma unroll
                for (int t = 0; t < BF; ++t)
                    hraw[t] = h8[(size_t)sid[t] * 64 + j];
                intx4 eav[BF];
                #pragma unroll
                for (int t = 0; t < BF; ++t)
                    eav[t] = __builtin_nontemporal_load(
                        (const intx4*)&ea16[(size_t)(base + t) * 8]);

                #pragma unroll
                for (int t = 0; t < BF; ++t) {
                    __half2 d = __hmul2(u2h(eav[t].x), w2[0]);
                    d = __hfma2(u2h(eav[t].y), w2[1], d);
                    d = __hfma2(u2h(eav[t].z), w2[2], d);
                    d = __hfma2(u2h(eav[t].w), w2[3], d);
                    float proj = __half2float(__low2half(d)) + __half2float(__high2half(d));
                    float hrf = __builtin_amdgcn_cvt_f32_fp8((int)hraw[t], 0);
                    float m = hrf + proj + bej;
                    acci += (int)((m > 0.0f ? m : 0.0f) * QSCALE);
                }
            }
            int end = start + dg;
            for (int idx = base; idx < end; ++idx) {
                int s = __builtin_amdgcn_readfirstlane(src_s[idx]);
                float hrf = __builtin_amdgcn_cvt_f32_fp8((int)h8[(size_t)s * 64 + j], 0);
                intx4 ev = __builtin_nontemporal_load((const intx4*)&ea16[(size_t)idx * 8]);
                __half2 d = __hmul2(u2h(ev.x), w2[0]);
                d = __hfma2(u2h(ev.y), w2[1], d);
                d = __hfma2(u2h(ev.z), w2[2], d);
                d = __hfma2(u2h(ev.w), w2[3], d);
                float proj = __half2float(__low2half(d)) + __half2float(__high2half(d));
                float m = hrf + proj + bej;
                acci += (int)((m > 0.0f ? m : 0.0f) * QSCALE);
            }
            xsl[nl][j] = (_Float16)(selff + (float)acci * QINV);
        }
    }
    __syncthreads();

    // ---------------- phase 2: MFMA on the 32-row LDS tile ----------------
    // Wave w computes col-tiles {2w, 2w+1}; same fragment mapping as the
    // verified node_mfma kernel (A row = node, C col = lane&15).
    int row16 = l & 15;
    int quad  = l >> 4;
    floatx4 accA[2], accB[2];
    #pragma unroll
    for (int t2 = 0; t2 < 2; ++t2) { accA[t2] = (floatx4)(0.0f); accB[t2] = (floatx4)(0.0f); }

    #pragma unroll
    for (int kc = 0; kc < K; kc += 32) {
        half8 a0 = *(const half8*)&xsl[row16][kc + quad * 8];
        half8 a1 = *(const half8*)&xsl[16 + row16][kc + quad * 8];
        #pragma unroll
        for (int t2 = 0; t2 < 2; ++t2) {
            int t = wave * 2 + t2;
            half8 bf = *(const half8*)&Wt[(size_t)(t * 16 + row16) * K + kc + quad * 8];
            accA[t2] = __builtin_amdgcn_mfma_f32_16x16x32_f16(a0, bf, accA[t2], 0, 0, 0);
            accB[t2] = __builtin_amdgcn_mfma_f32_16x16x32_f16(a1, bf, accB[t2], 0, 0, 0);
        }
    }

    #pragma unroll
    for (int t2 = 0; t2 < 2; ++t2) {
        int col = (wave * 2 + t2) * 16 + row16;
        float bj = bias[col];
        #pragma unroll
        for (int r = 0; r < 4; ++r) {
            int nodeA = m0 + quad * 4 + r;
            if (nodeA < N) {
                float v = accA[t2][r] + bj;
                v = v > 0.0f ? v : 0.0f;
                if (OUT8) out8[(size_t)nodeA * 128 + col] = f32_to_fp8(v);
                else      out16[(size_t)nodeA * 128 + col] = (_Float16)v;
            }
            int nodeB = m0 + 16 + quad * 4 + r;
            if (nodeB < N) {
                float v = accB[t2][r] + bj;
                v = v > 0.0f ? v : 0.0f;
                if (OUT8) out8[(size_t)nodeB * 128 + col] = f32_to_fp8(v);
                else      out16[(size_t)nodeB * 128 + col] = (_Float16)v;
            }
        }
    }
}

// ===========================================================================
// Pool: one block per graph; 256 threads = 4 node-streams x 64 feature-pairs.
// ===========================================================================
__global__ __launch_bounds__(256) void pool_kernel(
    const __half* __restrict__ h,      // [N, 128] fp16
    const int*    __restrict__ batch,  // [N] sorted
    float*        __restrict__ out,    // [G, 128]
    int N)
{
    __shared__ int s_lo, s_hi;
    __shared__ float part[4][128];
    int g  = blockIdx.x;
    int t  = threadIdx.x;
    int fp = t & 63;        // feature pair: features 2fp, 2fp+1
    int r  = t >> 6;        // node stream 0..3

    if (t == 0) {
        int lo = 0, hi = N;
        while (lo < hi) { int m = (lo + hi) >> 1; if (batch[m] < g) lo = m + 1; else hi = m; }
        s_lo = lo;
        int lo2 = lo, hi2 = N;
        while (lo2 < hi2) { int m = (lo2 + hi2) >> 1; if (batch[m] < g + 1) lo2 = m + 1; else hi2 = m; }
        s_hi = lo2;
    }
    __syncthreads();

    int lo = s_lo, hi = s_hi;
    float a0 = 0.0f, a1 = 0.0f;
    for (int n = lo + r; n < hi; n += 4) {
        float2 f = __half22float2(*(const __half2*)&h[(size_t)n * 128 + 2 * fp]);
        a0 += f.x; a1 += f.y;
    }
    part[r][2 * fp]     = a0;
    part[r][2 * fp + 1] = a1;
    __syncthreads();

    if (r == 0) {
        float s0 = part[0][2 * fp] + part[1][2 * fp] + part[2][2 * fp] + part[3][2 * fp];
        float s1 = part[0][2 * fp + 1] + part[1][2 * fp + 1] + part[2][2 * fp + 1] + part[3][2 * fp + 1];
        float c = (float)(hi - lo);
        float d = c > 1.0f ? c : 1.0f;
        out[g * HIDDEN + 2 * fp]     = s0 / d;
        out[g * HIDDEN + 2 * fp + 1] = s1 / d;
    }
}

// ===========================================================================
extern "C" void kernel_launch(void* const* d_in, const int* in_sizes, int n_in,
                              void* d_out, int out_size, void* d_ws, size_t ws_size,
                              hipStream_t stream)
{
    const float* x   = (const float*)d_in[0];      // [N, 64]
    const int*   ei  = (const int*)d_in[1];        // [2, E]
    const float* ea  = (const float*)d_in[2];      // [E, 8]
    const int*   bat = (const int*)d_in[3];        // [N]
    const float* W1  = (const float*)d_in[4];
    const float* b1  = (const float*)d_in[5];
    const float* We1 = (const float*)d_in[6];
    const float* be1 = (const float*)d_in[7];
    const float* W2  = (const float*)d_in[8];
    const float* b2  = (const float*)d_in[9];
    const float* We2 = (const float*)d_in[10];
    const float* be2 = (const float*)d_in[11];
    const float* W3  = (const float*)d_in[12];
    const float* b3  = (const float*)d_in[13];
    const float* We3 = (const float*)d_in[14];
    const float* be3 = (const float*)d_in[15];
    float* out = (float*)d_out;

    const int* src = ei;
    const int* dst = ei + N_EDGES;

    // ---------------- workspace layout ----------------
    int* deg       = (int*)d_ws;                             // [N]
    int* rowptr    = deg + N_NODES;                          // [N]
    int* pos       = rowptr + N_NODES;                       // [N]
    int* src_s     = pos + N_NODES;                          // [E]
    int* blockSums = src_s + N_EDGES;                        // [128]
    __half* ea16   = (__half*)(blockSums + 128);             // [E, 8] fp16
    __half* h3h    = ea16 + (size_t)N_EDGES * EDGE_DIM;      // [N,128] fp16 (layer-3 out)
    unsigned char* xh8  = (unsigned char*)(h3h + (size_t)N_NODES * HIDDEN); // [N,64] fp8
    unsigned char* h1_8 = xh8 + (size_t)N_NODES * IN_CH;     // [N,128] fp8
    unsigned char* h2_8 = h1_8 + (size_t)N_NODES * HIDDEN;   // [N,128] fp8
    _Float16* Wt1  = (_Float16*)(h2_8 + (size_t)N_NODES * HIDDEN); // [128,64]
    _Float16* Wt2  = Wt1 + 128 * IN_CH;                      // [128,128]
    _Float16* Wt3  = Wt2 + 128 * HIDDEN;                     // [128,128]

    const int BLK = 256;
    const int NB_E = (N_EDGES + BLK - 1) / BLK;
    const int NB_N = (N_NODES + BLK - 1) / BLK;
    const int SCAN_B = (N_NODES + 511) / 512;    // 98
    const int FUSED_B = (N_NODES + 31) / 32;     // 1563 (32 nodes/block)
    const int CVT_ELEMS = XH_ELEMS + 128 * IN_CH + 2 * 128 * HIDDEN;
    const int NB_HC = (CVT_ELEMS + BLK - 1) / BLK;   // covers E too (E < CVT_ELEMS)

    // ---------------- CSR build (sortless) + fp8/Wt conversion ------------
    (void)hipMemsetAsync(deg, 0, N_NODES * sizeof(int), stream);
    hist_cvt_kernel<<<NB_HC, BLK, 0, stream>>>(
        dst, deg, x, xh8, W1, W2, W3, Wt1, Wt2, Wt3, N_EDGES);
    scan1_kernel<<<SCAN_B, 256, 0, stream>>>(deg, pos, blockSums, N_NODES);
    scan2_kernel<<<1, 128, 0, stream>>>(blockSums, SCAN_B);
    scan3_kernel<<<NB_N, BLK, 0, stream>>>(pos, deg, blockSums, rowptr, pos, N_NODES);
    for (int pass = 0; pass < NPASS; ++pass) {
        scatter_rec_kernel<<<NB_E, BLK, 0, stream>>>(
            dst, src, ea, pos, src_s, ea16, pass * PASS_W, N_EDGES);
    }

    // ---------------- fused layers ----------------
    layer_fused_kernel<IN_CH, true><<<FUSED_B, 256, 0, stream>>>(
        xh8, src_s, ea16, rowptr, deg, We1, be1, Wt1, b1, nullptr, h1_8, N_NODES);
    layer_fused_kernel<HIDDEN, true><<<FUSED_B, 256, 0, stream>>>(
        h1_8, src_s, ea16, rowptr, deg, We2, be2, Wt2, b2, nullptr, h2_8, N_NODES);
    layer_fused_kernel<HIDDEN, false><<<FUSED_B, 256, 0, stream>>>(
        h2_8, src_s, ea16, rowptr, deg, We3, be3, Wt3, b3, (_Float16*)h3h, nullptr, N_NODES);

    // ---------------- global mean pool ----------------
    pool_kernel<<<NUM_GRAPHS, 256, 0, stream>>>(h3h, bat, out, N_NODES);
}

// Round 9
// 416.370 us; speedup vs baseline: 1.0098x; 1.0098x over previous
//
#include <hip/hip_runtime.h>
#include <hip/hip_bf16.h>
#include <hip/hip_fp16.h>

#define N_NODES 50000
#define N_EDGES 800000
#define IN_CH 64
#define EDGE_DIM 8
#define HIDDEN 128
#define NUM_GRAPHS 256
#define QSCALE 256.0f
#define QINV   (1.0f / 256.0f)

typedef __attribute__((ext_vector_type(8))) _Float16 half8;
typedef __attribute__((ext_vector_type(4))) float floatx4;
typedef __attribute__((ext_vector_type(2))) float floatx2;
typedef __attribute__((ext_vector_type(4))) int intx4;

static __device__ __forceinline__ __half2 u2h(int u) {
    union { int i; __half2 h; } cv; cv.i = u; return cv.h;
}
static __device__ __forceinline__ int h2u(__half2 h) {
    union { __half2 h; int i; } cv; cv.h = h; return cv.i;
}
static __device__ __forceinline__ unsigned short h1u(__half h) {
    union { __half h; unsigned short u; } cv; cv.h = h; return cv.u;
}
// fp8 e4m3 helpers (gfx950 OCP)
static __device__ __forceinline__ unsigned char f32_to_fp8(float v) {
    int pk = __builtin_amdgcn_cvt_pk_fp8_f32(v, v, 0, false);
    return (unsigned char)(pk & 0xff);
}

// ===========================================================================
// CSR build: histogram (fused with fp8/Wt conversions), scan, then a SINGLE
// full-range RECORD scatter pass. Edge order within a node = atomic arrival
// order (nondeterministic) -- harmless: gathers accumulate in int32 fixed
// point (order-insensitive).
// ===========================================================================
#define XH_ELEMS (N_NODES * IN_CH)

__global__ __launch_bounds__(256) void hist_cvt_kernel(
    const int* __restrict__ dst, int* __restrict__ deg,
    const float* __restrict__ x, unsigned char* __restrict__ xh8,
    const float* __restrict__ W1, const float* __restrict__ W2,
    const float* __restrict__ W3,
    _Float16* __restrict__ Wt1, _Float16* __restrict__ Wt2,
    _Float16* __restrict__ Wt3, int E)
{
    int i = blockIdx.x * blockDim.x + threadIdx.x;
    if (i < E) atomicAdd(&deg[dst[i]], 1);
    int idx = i;
    if (idx < XH_ELEMS) { xh8[idx] = f32_to_fp8(x[idx]); return; }
    idx -= XH_ELEMS;
    if (idx < 128 * IN_CH) {
        int n = idx / IN_CH, k = idx - n * IN_CH;
        Wt1[idx] = (_Float16)W1[k * 128 + n];
        return;
    }
    idx -= 128 * IN_CH;
    if (idx < 128 * HIDDEN) {
        int n = idx / HIDDEN, k = idx - n * HIDDEN;
        Wt2[idx] = (_Float16)W2[k * 128 + n];
        return;
    }
    idx -= 128 * HIDDEN;
    if (idx < 128 * HIDDEN) {
        int n = idx / HIDDEN, k = idx - n * HIDDEN;
        Wt3[idx] = (_Float16)W3[k * 128 + n];
    }
}

__global__ __launch_bounds__(256) void scan1_kernel(
    const int* __restrict__ deg, int* __restrict__ incl,
    int* __restrict__ blockSums, int N)
{
    __shared__ int s[256];
    int b = blockIdx.x, t = threadIdx.x;
    int i0 = b * 512 + 2 * t;
    int a0 = (i0 < N) ? deg[i0] : 0;
    int a1 = (i0 + 1 < N) ? deg[i0 + 1] : 0;
    int ps = a0 + a1;
    s[t] = ps;
    __syncthreads();
    for (int off = 1; off < 256; off <<= 1) {
        int v = (t >= off) ? s[t - off] : 0;
        __syncthreads();
        s[t] += v;
        __syncthreads();
    }
    int exclp = s[t] - ps;
    if (i0 < N)     incl[i0]     = exclp + a0;
    if (i0 + 1 < N) incl[i0 + 1] = exclp + a0 + a1;
    if (t == 255) blockSums[b] = s[255];
}

__global__ __launch_bounds__(128) void scan2_kernel(int* __restrict__ blockSums, int B)
{
    __shared__ int s[128];
    int t = threadIdx.x;
    int v = (t < B) ? blockSums[t] : 0;
    s[t] = v;
    __syncthreads();
    for (int off = 1; off < 128; off <<= 1) {
        int u = (t >= off) ? s[t - off] : 0;
        __syncthreads();
        s[t] += u;
        __syncthreads();
    }
    if (t < B) blockSums[t] = s[t] - v;   // exclusive
}

__global__ __launch_bounds__(256) void scan3_kernel(
    const int* __restrict__ incl, const int* __restrict__ deg,
    const int* __restrict__ blockSums, int* __restrict__ rowptr,
    int* __restrict__ pos, int N)
{
    int i = blockIdx.x * blockDim.x + threadIdx.x;
    if (i >= N) return;
    int v = incl[i] - deg[i] + blockSums[i >> 9];
    rowptr[i] = v;
    pos[i] = v;
}

// SINGLE full-range RECORD scatter pass (writes src_s + fp16 edge record).
__global__ __launch_bounds__(256) void scatter_rec_kernel(
    const int* __restrict__ dst, const int* __restrict__ src,
    const float* __restrict__ ea, int* __restrict__ pos,
    int* __restrict__ src_s, __half* __restrict__ ea16, int E)
{
    int e = blockIdx.x * blockDim.x + threadIdx.x;
    if (e >= E) return;
    int d = dst[e];
    int p = atomicAdd(&pos[d], 1);
    __builtin_nontemporal_store(src[e], &src_s[p]);
    const float4* q = (const float4*)(ea + (size_t)e * EDGE_DIM);
    float4 a = q[0], b = q[1];
    intx4 r;
    r.x = h2u(__floats2half2_rn(a.x, a.y));
    r.y = h2u(__floats2half2_rn(a.z, a.w));
    r.z = h2u(__floats2half2_rn(b.x, b.y));
    r.w = h2u(__floats2half2_rn(b.z, b.w));
    __builtin_nontemporal_store(r, (intx4*)(ea16 + (size_t)p * EDGE_DIM));
}

// ===========================================================================
// Gather-aggregate over FP8 h-table: 4 waves/block, one node/wave, 8 edges in
// flight. h rows are 128 B fp8 (2 lines/row). INT32 fixed-point acc ->
// order-insensitive.  (R7 verified structure, 60% occupancy.)
//   xs[n][j] = h[n][j] + sum_e relu( h[src][j] + (ea@We+be)[j] )   (fp16 out)
// ===========================================================================
#define BF 8   // edges in flight per wave

__global__ __launch_bounds__(256) void gather_xs128_kernel(
    const unsigned char* __restrict__ h8,   // [N,128] fp8
    const int*    __restrict__ src_s,       // [E] CSR order
    const __half* __restrict__ ea16,        // [E,8] fp16 CSR order
    const int*    __restrict__ rowptr,      // [N]
    const int*    __restrict__ deg,         // [N]
    const float*  __restrict__ We,          // [8,128]
    const float*  __restrict__ be,          // [128]
    __half*       __restrict__ xs,          // [N,128] fp16
    int N)
{
    int wave = threadIdx.x >> 6;
    int n    = blockIdx.x * 4 + wave;
    if (n >= N) return;
    int l  = threadIdx.x & 63;  // lane
    int j0 = 2 * l;

    __half2 hw[8];
    #pragma unroll
    for (int k = 0; k < 8; ++k) {
        float2 wv = *(const float2*)&We[k * 128 + j0];
        hw[k] = __floats2half2_rn(wv.x, wv.y);
    }
    float2 bevf = *(const float2*)&be[j0];
    __half2 bev2 = __floats2half2_rn(bevf.x, bevf.y);

    int start = __builtin_amdgcn_readfirstlane(rowptr[n]);
    int dg    = __builtin_amdgcn_readfirstlane(deg[n]);

    unsigned short selfraw = *(const unsigned short*)&h8[(size_t)n * 128 + j0];
    floatx2 hf = __builtin_amdgcn_cvt_pk_f32_fp8((int)selfraw, false);
    int acci0 = 0, acci1 = 0;          // fixed-point edge sum

    int nb = dg / BF;                  // full batches
    int base = start;
    for (int b = 0; b < nb; ++b, base += BF) {
        int sid[BF];
        #pragma unroll
        for (int t = 0; t < BF; ++t)
            sid[t] = __builtin_amdgcn_readfirstlane(
                __builtin_nontemporal_load(&src_s[base + t]));
        unsigned short hraw[BF];       // random 2B/lane loads (cached - hot)
        #pragma unroll
        for (int t = 0; t < BF; ++t)
            hraw[t] = *(const unsigned short*)&h8[(size_t)sid[t] * 128 + j0];
        intx4 eav[BF];                 // uniform streaming loads - nontemporal
        #pragma unroll
        for (int t = 0; t < BF; ++t)
            eav[t] = __builtin_nontemporal_load(
                (const intx4*)&ea16[(size_t)(base + t) * 8]);

        #pragma unroll
        for (int t = 0; t < BF; ++t) {
            __half2 e01 = u2h(eav[t].x), e23 = u2h(eav[t].y);
            __half2 e45 = u2h(eav[t].z), e67 = u2h(eav[t].w);
            __half2 m = __hfma2(__low2half2(e01),  hw[0], bev2);
            m = __hfma2(__high2half2(e01), hw[1], m);
            m = __hfma2(__low2half2(e23),  hw[2], m);
            m = __hfma2(__high2half2(e23), hw[3], m);
            m = __hfma2(__low2half2(e45),  hw[4], m);
            m = __hfma2(__high2half2(e45), hw[5], m);
            m = __hfma2(__low2half2(e67),  hw[6], m);
            m = __hfma2(__high2half2(e67), hw[7], m);
            floatx2 hs = __builtin_amdgcn_cvt_pk_f32_fp8((int)hraw[t], false);
            float m0 = __half2float(__low2half(m))  + hs.x;
            float m1 = __half2float(__high2half(m)) + hs.y;
            acci0 += (int)((m0 > 0.0f ? m0 : 0.0f) * QSCALE);
            acci1 += (int)((m1 > 0.0f ? m1 : 0.0f) * QSCALE);
        }
    }
    // tail (< BF edges)
    int end = start + dg;
    for (int idx = base; idx < end; ++idx) {
        int s = __builtin_amdgcn_readfirstlane(src_s[idx]);
        unsigned short hr = *(const unsigned short*)&h8[(size_t)s * 128 + j0];
        intx4 ev = __builtin_nontemporal_load((const intx4*)&ea16[(size_t)idx * 8]);
        __half2 e01 = u2h(ev.x), e23 = u2h(ev.y), e45 = u2h(ev.z), e67 = u2h(ev.w);
        __half2 m = __hfma2(__low2half2(e01),  hw[0], bev2);
        m = __hfma2(__high2half2(e01), hw[1], m);
        m = __hfma2(__low2half2(e23),  hw[2], m);
        m = __hfma2(__high2half2(e23), hw[3], m);
        m = __hfma2(__low2half2(e45),  hw[4], m);
        m = __hfma2(__high2half2(e45), hw[5], m);
        m = __hfma2(__low2half2(e67),  hw[6], m);
        m = __hfma2(__high2half2(e67), hw[7], m);
        floatx2 hs = __builtin_amdgcn_cvt_pk_f32_fp8((int)hr, false);
        float m0 = __half2float(__low2half(m))  + hs.x;
        float m1 = __half2float(__high2half(m)) + hs.y;
        acci0 += (int)((m0 > 0.0f ? m0 : 0.0f) * QSCALE);
        acci1 += (int)((m1 > 0.0f ? m1 : 0.0f) * QSCALE);
    }
    float acc0 = hf.x + (float)acci0 * QINV;
    float acc1 = hf.y + (float)acci1 * QINV;
    __builtin_nontemporal_store(h2u(__floats2half2_rn(acc0, acc1)),
                                (int*)&xs[(size_t)n * 128 + j0]);
}

// D=64 over fp8 x-table (64 B rows -> 1 line/row, 3.2 MB table: L2-resident).
__global__ __launch_bounds__(256) void gather_xs64_kernel(
    const unsigned char* __restrict__ h8,   // [N,64] fp8
    const int*    __restrict__ src_s,
    const __half* __restrict__ ea16,        // [E,8] fp16
    const int*    __restrict__ rowptr,
    const int*    __restrict__ deg,
    const float*  __restrict__ We,          // [8,64]
    const float*  __restrict__ be,          // [64]
    __half*       __restrict__ xs,          // [N,64] fp16
    int N)
{
    int wave = threadIdx.x >> 6;
    int n    = blockIdx.x * 4 + wave;
    if (n >= N) return;
    int j = threadIdx.x & 63;

    __half2 w2[4];
    #pragma unroll
    for (int p = 0; p < 4; ++p)
        w2[p] = __floats2half2_rn(We[(2 * p) * 64 + j], We[(2 * p + 1) * 64 + j]);
    float bej = be[j];

    int start = __builtin_amdgcn_readfirstlane(rowptr[n]);
    int dg    = __builtin_amdgcn_readfirstlane(deg[n]);

    float selff = __builtin_amdgcn_cvt_f32_fp8((int)h8[(size_t)n * 64 + j], 0);
    int acci = 0;

    int nb = dg / BF;
    int base = start;
    for (int b = 0; b < nb; ++b, base += BF) {
        int sid[BF];
        #pragma unroll
        for (int t = 0; t < BF; ++t)
            sid[t] = __builtin_amdgcn_readfirstlane(
                __builtin_nontemporal_load(&src_s[base + t]));
        unsigned char hraw[BF];
        #pragma unroll
        for (int t = 0; t < BF; ++t)
            hraw[t] = h8[(size_t)sid[t] * 64 + j];
        intx4 eav[BF];
        #pragma unroll
        for (int t = 0; t < BF; ++t)
            eav[t] = __builtin_nontemporal_load(
                (const intx4*)&ea16[(size_t)(base + t) * 8]);

        #pragma unroll
        for (int t = 0; t < BF; ++t) {
            __half2 d = __hmul2(u2h(eav[t].x), w2[0]);
            d = __hfma2(u2h(eav[t].y), w2[1], d);
            d = __hfma2(u2h(eav[t].z), w2[2], d);
            d = __hfma2(u2h(eav[t].w), w2[3], d);
            float proj = __half2float(__low2half(d)) + __half2float(__high2half(d));
            float hrf = __builtin_amdgcn_cvt_f32_fp8((int)hraw[t], 0);
            float m = hrf + proj + bej;
            acci += (int)((m > 0.0f ? m : 0.0f) * QSCALE);
        }
    }
    int end = start + dg;
    for (int idx = base; idx < end; ++idx) {
        int s = __builtin_amdgcn_readfirstlane(src_s[idx]);
        float hrf = __builtin_amdgcn_cvt_f32_fp8((int)h8[(size_t)s * 64 + j], 0);
        intx4 ev = __builtin_nontemporal_load((const intx4*)&ea16[(size_t)idx * 8]);
        __half2 d = __hmul2(u2h(ev.x), w2[0]);
        d = __hfma2(u2h(ev.y), w2[1], d);
        d = __hfma2(u2h(ev.z), w2[2], d);
        d = __hfma2(u2h(ev.w), w2[3], d);
        float proj = __half2float(__low2half(d)) + __half2float(__high2half(d));
        float m = hrf + proj + bej;
        acci += (int)((m > 0.0f ? m : 0.0f) * QSCALE);
    }
    float acc = selff + (float)acci * QINV;
    __builtin_nontemporal_store(h1u(__float2half(acc)),
                                (unsigned short*)&xs[(size_t)n * 64 + j]);
}

// ===========================================================================
// Node GEMM on matrix cores: out = relu(xs @ W + b), fp16 in, fp32 acc.
// OUT8: writes the fp8 gather table for the next layer (layers 1-2);
// else fp16 (layer 3, feeds pool).
// ===========================================================================
template<int K, bool OUT8>
__global__ __launch_bounds__(256) void node_mfma_kernel(
    const _Float16* __restrict__ xs,   // [N,K] fp16
    const _Float16* __restrict__ Wt,   // [128][K] fp16 (W transposed)
    const float*    __restrict__ b,    // [128]
    _Float16*       __restrict__ out16,   // [N,128] fp16 (if !OUT8)
    unsigned char*  __restrict__ out8,    // [N,128] fp8  (if OUT8)
    int N)
{
    int wave  = threadIdx.x >> 6;             // 0..3
    int lane  = threadIdx.x & 63;
    int row16 = lane & 15;
    int quad  = lane >> 4;
    int m0    = (blockIdx.x * 4 + wave) * 32;

    int nA = m0 + row16;        if (nA >= N) nA = N - 1;
    int nB = m0 + 16 + row16;   if (nB >= N) nB = N - 1;

    floatx4 accA[8], accB[8];
    #pragma unroll
    for (int t = 0; t < 8; ++t) { accA[t] = (floatx4)(0.0f); accB[t] = (floatx4)(0.0f); }

    #pragma unroll
    for (int kc = 0; kc < K; kc += 32) {
        half8 a0 = __builtin_nontemporal_load((const half8*)&xs[(size_t)nA * K + kc + quad * 8]);
        half8 a1 = __builtin_nontemporal_load((const half8*)&xs[(size_t)nB * K + kc + quad * 8]);
        #pragma unroll
        for (int t = 0; t < 8; ++t) {
            half8 bf = *(const half8*)&Wt[(size_t)(t * 16 + row16) * K + kc + quad * 8];
            accA[t] = __builtin_amdgcn_mfma_f32_16x16x32_f16(a0, bf, accA[t], 0, 0, 0);
            accB[t] = __builtin_amdgcn_mfma_f32_16x16x32_f16(a1, bf, accB[t], 0, 0, 0);
        }
    }

    #pragma unroll
    for (int t = 0; t < 8; ++t) {
        int col = t * 16 + row16;
        float bj = b[col];
        #pragma unroll
        for (int r = 0; r < 4; ++r) {
            int nodeA = m0 + quad * 4 + r;
            if (nodeA < N) {
                float v = accA[t][r] + bj;
                v = v > 0.0f ? v : 0.0f;
                if (OUT8) out8[(size_t)nodeA * 128 + col] = f32_to_fp8(v);
                else      out16[(size_t)nodeA * 128 + col] = (_Float16)v;
            }
            int nodeB = m0 + 16 + quad * 4 + r;
            if (nodeB < N) {
                float v = accB[t][r] + bj;
                v = v > 0.0f ? v : 0.0f;
                if (OUT8) out8[(size_t)nodeB * 128 + col] = f32_to_fp8(v);
                else      out16[(size_t)nodeB * 128 + col] = (_Float16)v;
            }
        }
    }
}

// ===========================================================================
// Pool: one block per graph; 256 threads = 4 node-streams x 64 feature-pairs.
// ===========================================================================
__global__ __launch_bounds__(256) void pool_kernel(
    const __half* __restrict__ h,      // [N, 128] fp16
    const int*    __restrict__ batch,  // [N] sorted
    float*        __restrict__ out,    // [G, 128]
    int N)
{
    __shared__ int s_lo, s_hi;
    __shared__ float part[4][128];
    int g  = blockIdx.x;
    int t  = threadIdx.x;
    int fp = t & 63;        // feature pair: features 2fp, 2fp+1
    int r  = t >> 6;        // node stream 0..3

    if (t == 0) {
        int lo = 0, hi = N;
        while (lo < hi) { int m = (lo + hi) >> 1; if (batch[m] < g) lo = m + 1; else hi = m; }
        s_lo = lo;
        int lo2 = lo, hi2 = N;
        while (lo2 < hi2) { int m = (lo2 + hi2) >> 1; if (batch[m] < g + 1) lo2 = m + 1; else hi2 = m; }
        s_hi = lo2;
    }
    __syncthreads();

    int lo = s_lo, hi = s_hi;
    float a0 = 0.0f, a1 = 0.0f;
    for (int n = lo + r; n < hi; n += 4) {
        float2 f = __half22float2(*(const __half2*)&h[(size_t)n * 128 + 2 * fp]);
        a0 += f.x; a1 += f.y;
    }
    part[r][2 * fp]     = a0;
    part[r][2 * fp + 1] = a1;
    __syncthreads();

    if (r == 0) {
        float s0 = part[0][2 * fp] + part[1][2 * fp] + part[2][2 * fp] + part[3][2 * fp];
        float s1 = part[0][2 * fp + 1] + part[1][2 * fp + 1] + part[2][2 * fp + 1] + part[3][2 * fp + 1];
        float c = (float)(hi - lo);
        float d = c > 1.0f ? c : 1.0f;
        out[g * HIDDEN + 2 * fp]     = s0 / d;
        out[g * HIDDEN + 2 * fp + 1] = s1 / d;
    }
}

// ===========================================================================
extern "C" void kernel_launch(void* const* d_in, const int* in_sizes, int n_in,
                              void* d_out, int out_size, void* d_ws, size_t ws_size,
                              hipStream_t stream)
{
    const float* x   = (const float*)d_in[0];      // [N, 64]
    const int*   ei  = (const int*)d_in[1];        // [2, E]
    const float* ea  = (const float*)d_in[2];      // [E, 8]
    const int*   bat = (const int*)d_in[3];        // [N]
    const float* W1  = (const float*)d_in[4];
    const float* b1  = (const float*)d_in[5];
    const float* We1 = (const float*)d_in[6];
    const float* be1 = (const float*)d_in[7];
    const float* W2  = (const float*)d_in[8];
    const float* b2  = (const float*)d_in[9];
    const float* We2 = (const float*)d_in[10];
    const float* be2 = (const float*)d_in[11];
    const float* W3  = (const float*)d_in[12];
    const float* b3  = (const float*)d_in[13];
    const float* We3 = (const float*)d_in[14];
    const float* be3 = (const float*)d_in[15];
    float* out = (float*)d_out;

    const int* src = ei;
    const int* dst = ei + N_EDGES;

    // ---------------- workspace layout ----------------
    int* deg       = (int*)d_ws;                             // [N]
    int* rowptr    = deg + N_NODES;                          // [N]
    int* pos       = rowptr + N_NODES;                       // [N]
    int* src_s     = pos + N_NODES;                          // [E]
    int* blockSums = src_s + N_EDGES;                        // [128]
    __half* ea16   = (__half*)(blockSums + 128);             // [E, 8] fp16
    __half* xs     = ea16 + (size_t)N_EDGES * EDGE_DIM;      // [N,128] fp16
    __half* h3h    = xs + (size_t)N_NODES * HIDDEN;          // [N,128] fp16 (layer-3 out)
    unsigned char* xh8  = (unsigned char*)(h3h + (size_t)N_NODES * HIDDEN); // [N,64] fp8
    unsigned char* h1_8 = xh8 + (size_t)N_NODES * IN_CH;     // [N,128] fp8
    unsigned char* h2_8 = h1_8 + (size_t)N_NODES * HIDDEN;   // [N,128] fp8
    _Float16* Wt1  = (_Float16*)(h2_8 + (size_t)N_NODES * HIDDEN); // [128,64]
    _Float16* Wt2  = Wt1 + 128 * IN_CH;                      // [128,128]
    _Float16* Wt3  = Wt2 + 128 * HIDDEN;                     // [128,128]

    const int BLK = 256;
    const int NB_E = (N_EDGES + BLK - 1) / BLK;
    const int NB_N = (N_NODES + BLK - 1) / BLK;
    const int SCAN_B = (N_NODES + 511) / 512;    // 98
    const int MFMA_B = (N_NODES + 127) / 128;    // 391
    const int WAVE4_B = (N_NODES + 3) / 4;       // 12500 (4 waves/block, 1 node/wave)
    const int CVT_ELEMS = XH_ELEMS + 128 * IN_CH + 2 * 128 * HIDDEN;
    const int NB_HC = (CVT_ELEMS + BLK - 1) / BLK;   // covers E too (E < CVT_ELEMS)

    // ---------------- CSR build (sortless, single scatter pass) -----------
    (void)hipMemsetAsync(deg, 0, N_NODES * sizeof(int), stream);
    hist_cvt_kernel<<<NB_HC, BLK, 0, stream>>>(
        dst, deg, x, xh8, W1, W2, W3, Wt1, Wt2, Wt3, N_EDGES);
    scan1_kernel<<<SCAN_B, 256, 0, stream>>>(deg, pos, blockSums, N_NODES);
    scan2_kernel<<<1, 128, 0, stream>>>(blockSums, SCAN_B);
    scan3_kernel<<<NB_N, BLK, 0, stream>>>(pos, deg, blockSums, rowptr, pos, N_NODES);
    scatter_rec_kernel<<<NB_E, BLK, 0, stream>>>(
        dst, src, ea, pos, src_s, ea16, N_EDGES);

    // ---------------- layer 1 (64 -> 128), fp8 out ----------------
    gather_xs64_kernel<<<WAVE4_B, BLK, 0, stream>>>(
        xh8, src_s, ea16, rowptr, deg, We1, be1, xs, N_NODES);
    node_mfma_kernel<IN_CH, true><<<MFMA_B, 256, 0, stream>>>(
        (const _Float16*)xs, Wt1, b1, nullptr, h1_8, N_NODES);

    // ---------------- layer 2 (128 -> 128), fp8 out ----------------
    gather_xs128_kernel<<<WAVE4_B, BLK, 0, stream>>>(
        h1_8, src_s, ea16, rowptr, deg, We2, be2, xs, N_NODES);
    node_mfma_kernel<HIDDEN, true><<<MFMA_B, 256, 0, stream>>>(
        (const _Float16*)xs, Wt2, b2, nullptr, h2_8, N_NODES);

    // ---------------- layer 3 (128 -> 128), fp16 out ----------------
    gather_xs128_kernel<<<WAVE4_B, BLK, 0, stream>>>(
        h2_8, src_s, ea16, rowptr, deg, We3, be3, xs, N_NODES);
    node_mfma_kernel<HIDDEN, false><<<MFMA_B, 256, 0, stream>>>(
        (const _Float16*)xs, Wt3, b3, (_Float16*)h3h, nullptr, N_NODES);

    // ---------------- global mean pool ----------------
    pool_kernel<<<NUM_GRAPHS, 256, 0, stream>>>(h3h, bat, out, N_NODES);
}

// Round 10
// 407.245 us; speedup vs baseline: 1.0325x; 1.0224x over previous
//
#include <hip/hip_runtime.h>
#include <hip/hip_bf16.h>
#include <hip/hip_fp16.h>

#define N_NODES 50000
#define N_EDGES 800000
#define IN_CH 64
#define EDGE_DIM 8
#define HIDDEN 128
#define NUM_GRAPHS 256
#define QSCALE 256.0f
#define QINV   (1.0f / 256.0f)

typedef __attribute__((ext_vector_type(8))) _Float16 half8;
typedef __attribute__((ext_vector_type(4))) float floatx4;
typedef __attribute__((ext_vector_type(2))) float floatx2;
typedef __attribute__((ext_vector_type(4))) int intx4;

static __device__ __forceinline__ __half2 u2h(int u) {
    union { int i; __half2 h; } cv; cv.i = u; return cv.h;
}
static __device__ __forceinline__ int h2u(__half2 h) {
    union { __half2 h; int i; } cv; cv.h = h; return cv.i;
}
static __device__ __forceinline__ unsigned short h1u(__half h) {
    union { __half h; unsigned short u; } cv; cv.h = h; return cv.u;
}
// fp8 e4m3 helpers (gfx950 OCP)
static __device__ __forceinline__ unsigned char f32_to_fp8(float v) {
    int pk = __builtin_amdgcn_cvt_pk_fp8_f32(v, v, 0, false);
    return (unsigned char)(pk & 0xff);
}

// ===========================================================================
// CSR build: histogram (fused with fp8/Wt conversions), scan, then a SINGLE
// full-range PACKED-RECORD scatter pass. Each edge writes ONE 32 B record
// {src, ea01, ea23, ea45, ea67} at its CSR slot -> one random cache line per
// edge (vs two with split src_s/ea16 arrays; R9 showed 5x write amp there).
// Edge order within a node = atomic arrival order (nondeterministic) --
// harmless: gathers accumulate in int32 fixed point (order-insensitive).
// ===========================================================================
#define XH_ELEMS (N_NODES * IN_CH)

__global__ __launch_bounds__(256) void hist_cvt_kernel(
    const int* __restrict__ dst, int* __restrict__ deg,
    const float* __restrict__ x, unsigned char* __restrict__ xh8,
    const float* __restrict__ W1, const float* __restrict__ W2,
    const float* __restrict__ W3,
    _Float16* __restrict__ Wt1, _Float16* __restrict__ Wt2,
    _Float16* __restrict__ Wt3, int E)
{
    int i = blockIdx.x * blockDim.x + threadIdx.x;
    if (i < E) atomicAdd(&deg[dst[i]], 1);
    int idx = i;
    if (idx < XH_ELEMS) { xh8[idx] = f32_to_fp8(x[idx]); return; }
    idx -= XH_ELEMS;
    if (idx < 128 * IN_CH) {
        int n = idx / IN_CH, k = idx - n * IN_CH;
        Wt1[idx] = (_Float16)W1[k * 128 + n];
        return;
    }
    idx -= 128 * IN_CH;
    if (idx < 128 * HIDDEN) {
        int n = idx / HIDDEN, k = idx - n * HIDDEN;
        Wt2[idx] = (_Float16)W2[k * 128 + n];
        return;
    }
    idx -= 128 * HIDDEN;
    if (idx < 128 * HIDDEN) {
        int n = idx / HIDDEN, k = idx - n * HIDDEN;
        Wt3[idx] = (_Float16)W3[k * 128 + n];
    }
}

__global__ __launch_bounds__(256) void scan1_kernel(
    const int* __restrict__ deg, int* __restrict__ incl,
    int* __restrict__ blockSums, int N)
{
    __shared__ int s[256];
    int b = blockIdx.x, t = threadIdx.x;
    int i0 = b * 512 + 2 * t;
    int a0 = (i0 < N) ? deg[i0] : 0;
    int a1 = (i0 + 1 < N) ? deg[i0 + 1] : 0;
    int ps = a0 + a1;
    s[t] = ps;
    __syncthreads();
    for (int off = 1; off < 256; off <<= 1) {
        int v = (t >= off) ? s[t - off] : 0;
        __syncthreads();
        s[t] += v;
        __syncthreads();
    }
    int exclp = s[t] - ps;
    if (i0 < N)     incl[i0]     = exclp + a0;
    if (i0 + 1 < N) incl[i0 + 1] = exclp + a0 + a1;
    if (t == 255) blockSums[b] = s[255];
}

__global__ __launch_bounds__(128) void scan2_kernel(int* __restrict__ blockSums, int B)
{
    __shared__ int s[128];
    int t = threadIdx.x;
    int v = (t < B) ? blockSums[t] : 0;
    s[t] = v;
    __syncthreads();
    for (int off = 1; off < 128; off <<= 1) {
        int u = (t >= off) ? s[t - off] : 0;
        __syncthreads();
        s[t] += u;
        __syncthreads();
    }
    if (t < B) blockSums[t] = s[t] - v;   // exclusive
}

__global__ __launch_bounds__(256) void scan3_kernel(
    const int* __restrict__ incl, const int* __restrict__ deg,
    const int* __restrict__ blockSums, int* __restrict__ rowptr,
    int* __restrict__ pos, int N)
{
    int i = blockIdx.x * blockDim.x + threadIdx.x;
    if (i >= N) return;
    int v = incl[i] - deg[i] + blockSums[i >> 9];
    rowptr[i] = v;
    pos[i] = v;
}

// SINGLE packed-record scatter pass: one 32 B record per edge, one line.
__global__ __launch_bounds__(256) void scatter_rec_kernel(
    const int* __restrict__ dst, const int* __restrict__ src,
    const float* __restrict__ ea, int* __restrict__ pos,
    int* __restrict__ rec, int E)
{
    int e = blockIdx.x * blockDim.x + threadIdx.x;
    if (e >= E) return;
    int d = dst[e];
    int p = atomicAdd(&pos[d], 1);
    const float4* q = (const float4*)(ea + (size_t)e * EDGE_DIM);
    float4 a = q[0], b = q[1];
    intx4 r;
    r.x = src[e];
    r.y = h2u(__floats2half2_rn(a.x, a.y));
    r.z = h2u(__floats2half2_rn(a.z, a.w));
    r.w = h2u(__floats2half2_rn(b.x, b.y));
    int* rp = rec + (size_t)p * 8;
    __builtin_nontemporal_store(r, (intx4*)rp);
    __builtin_nontemporal_store(h2u(__floats2half2_rn(b.z, b.w)), rp + 4);
}

// ===========================================================================
// Gather-aggregate over FP8 h-table + packed records: 4 waves/block, one
// node/wave, 8 edges in flight. INT32 fixed-point acc -> order-insensitive.
//   xs[n][j] = h[n][j] + sum_e relu( h[src][j] + (ea@We+be)[j] )   (fp16 out)
// ===========================================================================
#define BF 8   // edges in flight per wave

__global__ __launch_bounds__(256) void gather_xs128_kernel(
    const unsigned char* __restrict__ h8,   // [N,128] fp8
    const int*    __restrict__ rec,         // [E,8] packed records, CSR order
    const int*    __restrict__ rowptr,      // [N]
    const int*    __restrict__ deg,         // [N]
    const float*  __restrict__ We,          // [8,128]
    const float*  __restrict__ be,          // [128]
    __half*       __restrict__ xs,          // [N,128] fp16
    int N)
{
    int wave = threadIdx.x >> 6;
    int n    = blockIdx.x * 4 + wave;
    if (n >= N) return;
    int l  = threadIdx.x & 63;  // lane
    int j0 = 2 * l;

    __half2 hw[8];
    #pragma unroll
    for (int k = 0; k < 8; ++k) {
        float2 wv = *(const float2*)&We[k * 128 + j0];
        hw[k] = __floats2half2_rn(wv.x, wv.y);
    }
    float2 bevf = *(const float2*)&be[j0];
    __half2 bev2 = __floats2half2_rn(bevf.x, bevf.y);

    int start = __builtin_amdgcn_readfirstlane(rowptr[n]);
    int dg    = __builtin_amdgcn_readfirstlane(deg[n]);

    unsigned short selfraw = *(const unsigned short*)&h8[(size_t)n * 128 + j0];
    floatx2 hf = __builtin_amdgcn_cvt_pk_f32_fp8((int)selfraw, false);
    int acci0 = 0, acci1 = 0;          // fixed-point edge sum

    int nb = dg / BF;                  // full batches
    int base = start;
    for (int b = 0; b < nb; ++b, base += BF) {
        intx4 r0[BF]; int r1[BF];
        #pragma unroll
        for (int t = 0; t < BF; ++t)
            r0[t] = __builtin_nontemporal_load(
                (const intx4*)&rec[(size_t)(base + t) * 8]);
        #pragma unroll
        for (int t = 0; t < BF; ++t)
            r1[t] = __builtin_nontemporal_load(&rec[(size_t)(base + t) * 8 + 4]);
        int sid[BF];
        #pragma unroll
        for (int t = 0; t < BF; ++t)
            sid[t] = __builtin_amdgcn_readfirstlane(r0[t].x);
        unsigned short hraw[BF];       // random 2B/lane loads (cached - hot)
        #pragma unroll
        for (int t = 0; t < BF; ++t)
            hraw[t] = *(const unsigned short*)&h8[(size_t)sid[t] * 128 + j0];

        #pragma unroll
        for (int t = 0; t < BF; ++t) {
            __half2 e01 = u2h(r0[t].y), e23 = u2h(r0[t].z);
            __half2 e45 = u2h(r0[t].w), e67 = u2h(r1[t]);
            __half2 m = __hfma2(__low2half2(e01),  hw[0], bev2);
            m = __hfma2(__high2half2(e01), hw[1], m);
            m = __hfma2(__low2half2(e23),  hw[2], m);
            m = __hfma2(__high2half2(e23), hw[3], m);
            m = __hfma2(__low2half2(e45),  hw[4], m);
            m = __hfma2(__high2half2(e45), hw[5], m);
            m = __hfma2(__low2half2(e67),  hw[6], m);
            m = __hfma2(__high2half2(e67), hw[7], m);
            floatx2 hs = __builtin_amdgcn_cvt_pk_f32_fp8((int)hraw[t], false);
            float m0 = __half2float(__low2half(m))  + hs.x;
            float m1 = __half2float(__high2half(m)) + hs.y;
            acci0 += (int)((m0 > 0.0f ? m0 : 0.0f) * QSCALE);
            acci1 += (int)((m1 > 0.0f ? m1 : 0.0f) * QSCALE);
        }
    }
    // tail (< BF edges)
    int end = start + dg;
    for (int idx = base; idx < end; ++idx) {
        intx4 r0 = __builtin_nontemporal_load((const intx4*)&rec[(size_t)idx * 8]);
        int r1v  = __builtin_nontemporal_load(&rec[(size_t)idx * 8 + 4]);
        int s = __builtin_amdgcn_readfirstlane(r0.x);
        unsigned short hr = *(const unsigned short*)&h8[(size_t)s * 128 + j0];
        __half2 e01 = u2h(r0.y), e23 = u2h(r0.z), e45 = u2h(r0.w), e67 = u2h(r1v);
        __half2 m = __hfma2(__low2half2(e01),  hw[0], bev2);
        m = __hfma2(__high2half2(e01), hw[1], m);
        m = __hfma2(__low2half2(e23),  hw[2], m);
        m = __hfma2(__high2half2(e23), hw[3], m);
        m = __hfma2(__low2half2(e45),  hw[4], m);
        m = __hfma2(__high2half2(e45), hw[5], m);
        m = __hfma2(__low2half2(e67),  hw[6], m);
        m = __hfma2(__high2half2(e67), hw[7], m);
        floatx2 hs = __builtin_amdgcn_cvt_pk_f32_fp8((int)hr, false);
        float m0 = __half2float(__low2half(m))  + hs.x;
        float m1 = __half2float(__high2half(m)) + hs.y;
        acci0 += (int)((m0 > 0.0f ? m0 : 0.0f) * QSCALE);
        acci1 += (int)((m1 > 0.0f ? m1 : 0.0f) * QSCALE);
    }
    float acc0 = hf.x + (float)acci0 * QINV;
    float acc1 = hf.y + (float)acci1 * QINV;
    __builtin_nontemporal_store(h2u(__floats2half2_rn(acc0, acc1)),
                                (int*)&xs[(size_t)n * 128 + j0]);
}

// D=64 over fp8 x-table (64 B rows -> 1 line/row, 3.2 MB table: L2-resident).
__global__ __launch_bounds__(256) void gather_xs64_kernel(
    const unsigned char* __restrict__ h8,   // [N,64] fp8
    const int*    __restrict__ rec,         // [E,8] packed records
    const int*    __restrict__ rowptr,
    const int*    __restrict__ deg,
    const float*  __restrict__ We,          // [8,64]
    const float*  __restrict__ be,          // [64]
    __half*       __restrict__ xs,          // [N,64] fp16
    int N)
{
    int wave = threadIdx.x >> 6;
    int n    = blockIdx.x * 4 + wave;
    if (n >= N) return;
    int j = threadIdx.x & 63;

    __half2 w2[4];
    #pragma unroll
    for (int p = 0; p < 4; ++p)
        w2[p] = __floats2half2_rn(We[(2 * p) * 64 + j], We[(2 * p + 1) * 64 + j]);
    float bej = be[j];

    int start = __builtin_amdgcn_readfirstlane(rowptr[n]);
    int dg    = __builtin_amdgcn_readfirstlane(deg[n]);

    float selff = __builtin_amdgcn_cvt_f32_fp8((int)h8[(size_t)n * 64 + j], 0);
    int acci = 0;

    int nb = dg / BF;
    int base = start;
    for (int b = 0; b < nb; ++b, base += BF) {
        intx4 r0[BF]; int r1[BF];
        #pragma unroll
        for (int t = 0; t < BF; ++t)
            r0[t] = __builtin_nontemporal_load(
                (const intx4*)&rec[(size_t)(base + t) * 8]);
        #pragma unroll
        for (int t = 0; t < BF; ++t)
            r1[t] = __builtin_nontemporal_load(&rec[(size_t)(base + t) * 8 + 4]);
        int sid[BF];
        #pragma unroll
        for (int t = 0; t < BF; ++t)
            sid[t] = __builtin_amdgcn_readfirstlane(r0[t].x);
        unsigned char hraw[BF];
        #pragma unroll
        for (int t = 0; t < BF; ++t)
            hraw[t] = h8[(size_t)sid[t] * 64 + j];

        #pragma unroll
        for (int t = 0; t < BF; ++t) {
            __half2 d = __hmul2(u2h(r0[t].y), w2[0]);
            d = __hfma2(u2h(r0[t].z), w2[1], d);
            d = __hfma2(u2h(r0[t].w), w2[2], d);
            d = __hfma2(u2h(r1[t]),   w2[3], d);
            float proj = __half2float(__low2half(d)) + __half2float(__high2half(d));
            float hrf = __builtin_amdgcn_cvt_f32_fp8((int)hraw[t], 0);
            float m = hrf + proj + bej;
            acci += (int)((m > 0.0f ? m : 0.0f) * QSCALE);
        }
    }
    int end = start + dg;
    for (int idx = base; idx < end; ++idx) {
        intx4 r0 = __builtin_nontemporal_load((const intx4*)&rec[(size_t)idx * 8]);
        int r1v  = __builtin_nontemporal_load(&rec[(size_t)idx * 8 + 4]);
        int s = __builtin_amdgcn_readfirstlane(r0.x);
        float hrf = __builtin_amdgcn_cvt_f32_fp8((int)h8[(size_t)s * 64 + j], 0);
        __half2 d = __hmul2(u2h(r0.y), w2[0]);
        d = __hfma2(u2h(r0.z), w2[1], d);
        d = __hfma2(u2h(r0.w), w2[2], d);
        d = __hfma2(u2h(r1v),  w2[3], d);
        float proj = __half2float(__low2half(d)) + __half2float(__high2half(d));
        float m = hrf + proj + bej;
        acci += (int)((m > 0.0f ? m : 0.0f) * QSCALE);
    }
    float acc = selff + (float)acci * QINV;
    __builtin_nontemporal_store(h1u(__float2half(acc)),
                                (unsigned short*)&xs[(size_t)n * 64 + j]);
}

// ===========================================================================
// Node GEMM on matrix cores: out = relu(xs @ W + b), fp16 in, fp32 acc.
// OUT8: writes the fp8 gather table for the next layer (layers 1-2);
// else fp16 (layer 3, feeds pool).
// ===========================================================================
template<int K, bool OUT8>
__global__ __launch_bounds__(256) void node_mfma_kernel(
    const _Float16* __restrict__ xs,   // [N,K] fp16
    const _Float16* __restrict__ Wt,   // [128][K] fp16 (W transposed)
    const float*    __restrict__ b,    // [128]
    _Float16*       __restrict__ out16,   // [N,128] fp16 (if !OUT8)
    unsigned char*  __restrict__ out8,    // [N,128] fp8  (if OUT8)
    int N)
{
    int wave  = threadIdx.x >> 6;             // 0..3
    int lane  = threadIdx.x & 63;
    int row16 = lane & 15;
    int quad  = lane >> 4;
    int m0    = (blockIdx.x * 4 + wave) * 32;

    int nA = m0 + row16;        if (nA >= N) nA = N - 1;
    int nB = m0 + 16 + row16;   if (nB >= N) nB = N - 1;

    floatx4 accA[8], accB[8];
    #pragma unroll
    for (int t = 0; t < 8; ++t) { accA[t] = (floatx4)(0.0f); accB[t] = (floatx4)(0.0f); }

    #pragma unroll
    for (int kc = 0; kc < K; kc += 32) {
        half8 a0 = __builtin_nontemporal_load((const half8*)&xs[(size_t)nA * K + kc + quad * 8]);
        half8 a1 = __builtin_nontemporal_load((const half8*)&xs[(size_t)nB * K + kc + quad * 8]);
        #pragma unroll
        for (int t = 0; t < 8; ++t) {
            half8 bf = *(const half8*)&Wt[(size_t)(t * 16 + row16) * K + kc + quad * 8];
            accA[t] = __builtin_amdgcn_mfma_f32_16x16x32_f16(a0, bf, accA[t], 0, 0, 0);
            accB[t] = __builtin_amdgcn_mfma_f32_16x16x32_f16(a1, bf, accB[t], 0, 0, 0);
        }
    }

    #pragma unroll
    for (int t = 0; t < 8; ++t) {
        int col = t * 16 + row16;
        float bj = b[col];
        #pragma unroll
        for (int r = 0; r < 4; ++r) {
            int nodeA = m0 + quad * 4 + r;
            if (nodeA < N) {
                float v = accA[t][r] + bj;
                v = v > 0.0f ? v : 0.0f;
                if (OUT8) out8[(size_t)nodeA * 128 + col] = f32_to_fp8(v);
                else      out16[(size_t)nodeA * 128 + col] = (_Float16)v;
            }
            int nodeB = m0 + 16 + quad * 4 + r;
            if (nodeB < N) {
                float v = accB[t][r] + bj;
                v = v > 0.0f ? v : 0.0f;
                if (OUT8) out8[(size_t)nodeB * 128 + col] = f32_to_fp8(v);
                else      out16[(size_t)nodeB * 128 + col] = (_Float16)v;
            }
        }
    }
}

// ===========================================================================
// Pool: one block per graph; 256 threads = 4 node-streams x 64 feature-pairs.
// ===========================================================================
__global__ __launch_bounds__(256) void pool_kernel(
    const __half* __restrict__ h,      // [N, 128] fp16
    const int*    __restrict__ batch,  // [N] sorted
    float*        __restrict__ out,    // [G, 128]
    int N)
{
    __shared__ int s_lo, s_hi;
    __shared__ float part[4][128];
    int g  = blockIdx.x;
    int t  = threadIdx.x;
    int fp = t & 63;        // feature pair: features 2fp, 2fp+1
    int r  = t >> 6;        // node stream 0..3

    if (t == 0) {
        int lo = 0, hi = N;
        while (lo < hi) { int m = (lo + hi) >> 1; if (batch[m] < g) lo = m + 1; else hi = m; }
        s_lo = lo;
        int lo2 = lo, hi2 = N;
        while (lo2 < hi2) { int m = (lo2 + hi2) >> 1; if (batch[m] < g + 1) lo2 = m + 1; else hi2 = m; }
        s_hi = lo2;
    }
    __syncthreads();

    int lo = s_lo, hi = s_hi;
    float a0 = 0.0f, a1 = 0.0f;
    for (int n = lo + r; n < hi; n += 4) {
        float2 f = __half22float2(*(const __half2*)&h[(size_t)n * 128 + 2 * fp]);
        a0 += f.x; a1 += f.y;
    }
    part[r][2 * fp]     = a0;
    part[r][2 * fp + 1] = a1;
    __syncthreads();

    if (r == 0) {
        float s0 = part[0][2 * fp] + part[1][2 * fp] + part[2][2 * fp] + part[3][2 * fp];
        float s1 = part[0][2 * fp + 1] + part[1][2 * fp + 1] + part[2][2 * fp + 1] + part[3][2 * fp + 1];
        float c = (float)(hi - lo);
        float d = c > 1.0f ? c : 1.0f;
        out[g * HIDDEN + 2 * fp]     = s0 / d;
        out[g * HIDDEN + 2 * fp + 1] = s1 / d;
    }
}

// ===========================================================================
extern "C" void kernel_launch(void* const* d_in, const int* in_sizes, int n_in,
                              void* d_out, int out_size, void* d_ws, size_t ws_size,
                              hipStream_t stream)
{
    const float* x   = (const float*)d_in[0];      // [N, 64]
    const int*   ei  = (const int*)d_in[1];        // [2, E]
    const float* ea  = (const float*)d_in[2];      // [E, 8]
    const int*   bat = (const int*)d_in[3];        // [N]
    const float* W1  = (const float*)d_in[4];
    const float* b1  = (const float*)d_in[5];
    const float* We1 = (const float*)d_in[6];
    const float* be1 = (const float*)d_in[7];
    const float* W2  = (const float*)d_in[8];
    const float* b2  = (const float*)d_in[9];
    const float* We2 = (const float*)d_in[10];
    const float* be2 = (const float*)d_in[11];
    const float* W3  = (const float*)d_in[12];
    const float* b3  = (const float*)d_in[13];
    const float* We3 = (const float*)d_in[14];
    const float* be3 = (const float*)d_in[15];
    float* out = (float*)d_out;

    const int* src = ei;
    const int* dst = ei + N_EDGES;

    // ---------------- workspace layout ----------------
    int* deg       = (int*)d_ws;                             // [N]
    int* rowptr    = deg + N_NODES;                          // [N]
    int* pos       = rowptr + N_NODES;                       // [N]
    int* blockSums = pos + N_NODES;                          // [128]
    int* rec       = blockSums + 128;                        // [E,8] packed 32B records
    __half* xs     = (__half*)(rec + (size_t)N_EDGES * 8);   // [N,128] fp16
    __half* h3h    = xs + (size_t)N_NODES * HIDDEN;          // [N,128] fp16 (layer-3 out)
    unsigned char* xh8  = (unsigned char*)(h3h + (size_t)N_NODES * HIDDEN); // [N,64] fp8
    unsigned char* h1_8 = xh8 + (size_t)N_NODES * IN_CH;     // [N,128] fp8
    unsigned char* h2_8 = h1_8 + (size_t)N_NODES * HIDDEN;   // [N,128] fp8
    _Float16* Wt1  = (_Float16*)(h2_8 + (size_t)N_NODES * HIDDEN); // [128,64]
    _Float16* Wt2  = Wt1 + 128 * IN_CH;                      // [128,128]
    _Float16* Wt3  = Wt2 + 128 * HIDDEN;                     // [128,128]

    const int BLK = 256;
    const int NB_E = (N_EDGES + BLK - 1) / BLK;
    const int NB_N = (N_NODES + BLK - 1) / BLK;
    const int SCAN_B = (N_NODES + 511) / 512;    // 98
    const int MFMA_B = (N_NODES + 127) / 128;    // 391
    const int WAVE4_B = (N_NODES + 3) / 4;       // 12500 (4 waves/block, 1 node/wave)
    const int CVT_ELEMS = XH_ELEMS + 128 * IN_CH + 2 * 128 * HIDDEN;
    const int NB_HC = (CVT_ELEMS + BLK - 1) / BLK;   // covers E too (E < CVT_ELEMS)

    // ---------------- CSR build (sortless, single packed scatter) ---------
    (void)hipMemsetAsync(deg, 0, N_NODES * sizeof(int), stream);
    hist_cvt_kernel<<<NB_HC, BLK, 0, stream>>>(
        dst, deg, x, xh8, W1, W2, W3, Wt1, Wt2, Wt3, N_EDGES);
    scan1_kernel<<<SCAN_B, 256, 0, stream>>>(deg, pos, blockSums, N_NODES);
    scan2_kernel<<<1, 128, 0, stream>>>(blockSums, SCAN_B);
    scan3_kernel<<<NB_N, BLK, 0, stream>>>(pos, deg, blockSums, rowptr, pos, N_NODES);
    scatter_rec_kernel<<<NB_E, BLK, 0, stream>>>(
        dst, src, ea, pos, rec, N_EDGES);

    // ---------------- layer 1 (64 -> 128), fp8 out ----------------
    gather_xs64_kernel<<<WAVE4_B, BLK, 0, stream>>>(
        xh8, rec, rowptr, deg, We1, be1, xs, N_NODES);
    node_mfma_kernel<IN_CH, true><<<MFMA_B, 256, 0, stream>>>(
        (const _Float16*)xs, Wt1, b1, nullptr, h1_8, N_NODES);

    // ---------------- layer 2 (128 -> 128), fp8 out ----------------
    gather_xs128_kernel<<<WAVE4_B, BLK, 0, stream>>>(
        h1_8, rec, rowptr, deg, We2, be2, xs, N_NODES);
    node_mfma_kernel<HIDDEN, true><<<MFMA_B, 256, 0, stream>>>(
        (const _Float16*)xs, Wt2, b2, nullptr, h2_8, N_NODES);

    // ---------------- layer 3 (128 -> 128), fp16 out ----------------
    gather_xs128_kernel<<<WAVE4_B, BLK, 0, stream>>>(
        h2_8, rec, rowptr, deg, We3, be3, xs, N_NODES);
    node_mfma_kernel<HIDDEN, false><<<MFMA_B, 256, 0, stream>>>(
        (const _Float16*)xs, Wt3, b3, (_Float16*)h3h, nullptr, N_NODES);

    // ---------------- global mean pool ----------------
    pool_kernel<<<NUM_GRAPHS, 256, 0, stream>>>(h3h, bat, out, N_NODES);
}